// Round 16
// baseline (60.686 us; speedup 1.0000x reference)
//
#include <hip/hip_runtime.h>
#include <hip/hip_bf16.h>

// BatchAllTripletLoss, B=512, E=128, labels in [0,64), MARGIN=1.0, EPS=1e-16.
// K1 fused_rows (32 blocks x 256 thr, 16 anchors/block):
//   - stage bf16(-2*anchor) tile + exact fp32 norms (proven shfl pattern)
//   - stream all 512 emb rows in 4 super-chunks of 128: coalesced float4,
//     bf16 convert to LDS, exact fp32 row norms
//   - MFMA 16x16x32 per chunk (operands/layout/K-order identical to proven
//     R10 dist_mfma -> bit-identical distances), dist rows kept in LDS
//   - ballots -> plist -> hinge -> block reduce -> 1 partial pair per block
// K2 finalize32: 1 block reduces 32 partials -> out[0].
// No atomics, no D round-trip, deterministic.

#define BSZ 512
#define EDIM 128
#define NANCH 16
#define NPOS 64

typedef __attribute__((ext_vector_type(8))) short short8;
typedef __attribute__((ext_vector_type(4))) float f32x4;

__device__ __forceinline__ unsigned short f2bf(float f) {
    __hip_bfloat16 h = __float2bfloat16(f);
    return *reinterpret_cast<unsigned short*>(&h);
}

__global__ __launch_bounds__(256) void fused_rows(
    const float* __restrict__ embs,
    const int* __restrict__ labels,
    float* __restrict__ sums,
    float* __restrict__ cnts)
{
    __shared__ unsigned short Abf[NANCH][136];   // bf16(-2*anchor), +pad
    __shared__ unsigned short Bbf[128][136];     // bf16(emb chunk), +pad
    __shared__ float dsh[NANCH][516];            // dist rows, +4 pad (bank-spread)
    __shared__ float nA[NANCH], nB[128];
    __shared__ int   lab[BSZ];
    __shared__ unsigned long long masks[NANCH][8];
    __shared__ int   plist[NANCH][NPOS];
    __shared__ int   npsh[NANCH];
    __shared__ float wsum[4];
    __shared__ int   wcnt[4];

    const int tid = threadIdx.x;
    const int wv = tid >> 6, lane = tid & 63;
    const int A0 = blockIdx.x * NANCH;
    const int l15 = lane & 15, lk = lane >> 4;
    const float4* E4 = reinterpret_cast<const float4*>(embs);

    lab[tid]       = labels[tid];
    lab[tid + 256] = labels[tid + 256];

    // ---- stage anchors: bf16(-2*e) + exact fp32 norms ----
#pragma unroll
    for (int q = 0; q < 2; ++q) {
        int idx = tid + 256 * q;          // 0..511
        int r = idx >> 5, k4 = idx & 31;  // r 0..15
        float4 v = E4[(size_t)(A0 + r) * (EDIM / 4) + k4];
        float s = v.x * v.x + v.y * v.y + v.z * v.z + v.w * v.w;
        s += __shfl_xor(s, 1); s += __shfl_xor(s, 2); s += __shfl_xor(s, 4);
        s += __shfl_xor(s, 8); s += __shfl_xor(s, 16);
        if ((tid & 31) == 0) nA[r] = s;
        ushort4 u = { f2bf(-2.f * v.x), f2bf(-2.f * v.y),
                      f2bf(-2.f * v.z), f2bf(-2.f * v.w) };
        *reinterpret_cast<ushort4*>(&Abf[r][k4 * 4]) = u;
    }

    // ---- stream 4 super-chunks of 128 rows; MFMA into dsh ----
    for (int sc = 0; sc < 4; ++sc) {
#pragma unroll
        for (int q = 0; q < 16; ++q) {
            int idx = tid + 256 * q;          // 0..4095
            int r = idx >> 5, k4 = idx & 31;  // r 0..127
            float4 v = E4[(size_t)(sc * 128 + r) * (EDIM / 4) + k4];
            float s = v.x * v.x + v.y * v.y + v.z * v.z + v.w * v.w;
            s += __shfl_xor(s, 1); s += __shfl_xor(s, 2); s += __shfl_xor(s, 4);
            s += __shfl_xor(s, 8); s += __shfl_xor(s, 16);
            if ((tid & 31) == 0) nB[r] = s;
            ushort4 u = { f2bf(v.x), f2bf(v.y), f2bf(v.z), f2bf(v.w) };
            *reinterpret_cast<ushort4*>(&Bbf[r][k4 * 4]) = u;
        }
        __syncthreads();   // chunk (and on sc=0, anchors) staged

        // wave wv owns chunk rows [wv*32, wv*32+32): two 16-col MFMA tiles
#pragma unroll
        for (int half = 0; half < 2; ++half) {
            const int cl = wv * 32 + half * 16 + l15;   // chunk-local col
            f32x4 acc;
#pragma unroll
            for (int reg = 0; reg < 4; ++reg)
                acc[reg] = nA[lk * 4 + reg] + nB[cl];

            const unsigned short* arow = &Abf[l15][0];
            const unsigned short* brow = &Bbf[cl][0];
#pragma unroll
            for (int ks = 0; ks < 4; ++ks) {
                short8 af = *reinterpret_cast<const short8*>(arow + ks * 32 + lk * 8);
                short8 bf = *reinterpret_cast<const short8*>(brow + ks * 32 + lk * 8);
                acc = __builtin_amdgcn_mfma_f32_16x16x32_bf16(af, bf, acc, 0, 0, 0);
            }
#pragma unroll
            for (int reg = 0; reg < 4; ++reg)
                dsh[lk * 4 + reg][sc * 128 + cl] = fmaxf(acc[reg], 0.f);
        }
        __syncthreads();   // MFMA done before chunk buffer reuse
    }

    // ---- ballots: wave wv handles anchors wv*4..wv*4+3 ----
#pragma unroll
    for (int aa = 0; aa < 4; ++aa) {
        int a = wv * 4 + aa, ga = A0 + a, la = lab[ga];
#pragma unroll
        for (int c = 0; c < 8; ++c) {
            int j = c * 64 + lane;
            unsigned long long m = __ballot(lab[j] == la && j != ga);
            if (lane == 0) masks[a][c] = m;
        }
    }
    __syncthreads();

    // ---- positive lists (16 parallel walks) ----
    if (tid < NANCH) {
        int cp = 0;
#pragma unroll
        for (int w = 0; w < 8; ++w) {
            unsigned long long m = masks[tid][w];
            while (m) {
                int b = __builtin_ctzll(m);
                m &= m - 1;
                if (cp < NPOS) plist[tid][cp] = w * 64 + b;
                ++cp;
            }
        }
        npsh[tid] = cp < NPOS ? cp : NPOS;
    }
    __syncthreads();

    // ---- hinge: thread (a = tid>>4, col group tid&15) ----
    const int a  = tid >> 4;
    const int la = lab[A0 + a];
    const int np = npsh[a];
    float s = 0.f;
    int   c = 0;
    for (int h = 0; h < 32; ++h) {
        int n = (tid & 15) + 16 * h;
        if (lab[n] != la) {
            float dn = dsh[a][n];
            for (int i = 0; i < np; ++i) {
                float t = fmaxf(dsh[a][plist[a][i]] - dn + 1.0f, 0.f);
                s += t; c += (t > 1e-16f) ? 1 : 0;
            }
        }
    }

    // ---- block reduce ----
#pragma unroll
    for (int off = 32; off; off >>= 1) {
        s += __shfl_down(s, off);
        c += __shfl_down(c, off);
    }
    if (lane == 0) { wsum[wv] = s; wcnt[wv] = c; }
    __syncthreads();
    if (tid == 0) {
        sums[blockIdx.x] = wsum[0] + wsum[1] + wsum[2] + wsum[3];
        cnts[blockIdx.x] = (float)(wcnt[0] + wcnt[1] + wcnt[2] + wcnt[3]);
    }
}

__global__ __launch_bounds__(64) void finalize32(
    const float* __restrict__ sums,
    const float* __restrict__ cnts,
    float* __restrict__ out)
{
    const int lane = threadIdx.x;
    float s = (lane < 32) ? sums[lane] : 0.f;
    float c = (lane < 32) ? cnts[lane] : 0.f;
#pragma unroll
    for (int off = 32; off; off >>= 1) {
        s += __shfl_down(s, off);
        c += __shfl_down(c, off);
    }
    if (lane == 0) out[0] = s / (c + 1e-16f);
}

extern "C" void kernel_launch(void* const* d_in, const int* in_sizes, int n_in,
                              void* d_out, int out_size, void* d_ws, size_t ws_size,
                              hipStream_t stream)
{
    const float* embs   = reinterpret_cast<const float*>(d_in[0]);
    const int*   labels = reinterpret_cast<const int*>(d_in[1]);
    float*       out    = reinterpret_cast<float*>(d_out);

    float* sums = reinterpret_cast<float*>(d_ws);   // 32 floats
    float* cnts = sums + 32;                         // 32 floats

    fused_rows<<<32, 256, 0, stream>>>(embs, labels, sums, cnts);
    finalize32<<<1, 64, 0, stream>>>(sums, cnts, out);
}

// Round 17
// 25.795 us; speedup vs baseline: 2.3526x; 2.3526x over previous
//
#include <hip/hip_runtime.h>
#include <hip/hip_bf16.h>

// BatchAllTripletLoss, B=512, E=128, labels in [0,64), MARGIN=1.0, EPS=1e-16.
// K1 dist_mfma_sym: 136 upper-triangle 32x32 tiles via bf16 MFMA (proven R14).
//                   Block 0 zeroes the 2 u64 accumulators (K1 completes
//                   before K2 in stream order -> visible, proven R13).
// K2 triplet_pass:  proven R14 (512 blocks, 1 anchor each) + fused finalize:
//                   cnt atomicAdd; s_waitcnt vmcnt(0) (NO threadfence = no
//                   L2 writeback); ONE packed sum atomicAdd whose top 10 bits
//                   count arrivals -- the 512th add's return value identifies
//                   the last block AND carries the complete sum. Last block
//                   reads cnt (all count-adds provably performed) and writes
//                   out[0]. Integer adds = order-independent = deterministic.

#define BSZ 512
#define EDIM 128
#define TS 32
#define NPOSMAX 96
#define FPSCALE 1048576.0           // 2^20
#define ARRSHIFT 54                 // arrivals in bits [63:54]

typedef __attribute__((ext_vector_type(8))) short short8;
typedef __attribute__((ext_vector_type(4))) float f32x4;

__device__ __forceinline__ unsigned short f2bf(float f) {
    __hip_bfloat16 h = __float2bfloat16(f);
    return *reinterpret_cast<unsigned short*>(&h);
}

__global__ __launch_bounds__(256) void dist_mfma_sym(
    const float* __restrict__ embs,
    float* __restrict__ D,
    unsigned long long* __restrict__ accs)   // [0]=packed sum+arrivals, [1]=cnt
{
    __shared__ unsigned short Abf[TS][136];
    __shared__ unsigned short Bbf[TS][136];   // holds -2*b (exact scale)
    __shared__ float nA[TS], nB[TS];

    const int tid = threadIdx.x;
    if (blockIdx.x == 0 && tid < 2) accs[tid] = 0ull;

    // triangular decode: block t -> (bi, bj), bi <= bj
    int t = blockIdx.x, bi = 0;
    while (t >= 16 - bi) { t -= 16 - bi; ++bi; }
    const int bj = bi + t;
    const int I = bi * TS, J = bj * TS;
    const int wv = tid >> 6, lane = tid & 63;

    const float4* E4 = reinterpret_cast<const float4*>(embs);

    // ---- stage fp32 -> bf16 LDS + exact fp32 norms ----
#pragma unroll
    for (int q = 0; q < 4; ++q) {
        int idx = tid + 256 * q;
        int r   = idx >> 5;
        int k4  = idx & 31;

        float4 va = E4[(size_t)(I + r) * (EDIM / 4) + k4];
        float sa = va.x * va.x + va.y * va.y + va.z * va.z + va.w * va.w;
        sa += __shfl_xor(sa, 1); sa += __shfl_xor(sa, 2); sa += __shfl_xor(sa, 4);
        sa += __shfl_xor(sa, 8); sa += __shfl_xor(sa, 16);
        if ((tid & 31) == 0) nA[r] = sa;
        ushort4 ua = { f2bf(va.x), f2bf(va.y), f2bf(va.z), f2bf(va.w) };
        *reinterpret_cast<ushort4*>(&Abf[r][k4 * 4]) = ua;

        float4 vb = E4[(size_t)(J + r) * (EDIM / 4) + k4];
        float sb = vb.x * vb.x + vb.y * vb.y + vb.z * vb.z + vb.w * vb.w;
        sb += __shfl_xor(sb, 1); sb += __shfl_xor(sb, 2); sb += __shfl_xor(sb, 4);
        sb += __shfl_xor(sb, 8); sb += __shfl_xor(sb, 16);
        if ((tid & 31) == 0) nB[r] = sb;
        ushort4 ub = { f2bf(-2.f * vb.x), f2bf(-2.f * vb.y),
                       f2bf(-2.f * vb.z), f2bf(-2.f * vb.w) };
        *reinterpret_cast<ushort4*>(&Bbf[r][k4 * 4]) = ub;
    }
    __syncthreads();

    // ---- MFMA quadrant (wv): acc init = nA[row]+nB[col] ----
    const int qi = wv >> 1, qj = wv & 1;
    const int l15 = lane & 15, lk = lane >> 4;

    f32x4 acc;
#pragma unroll
    for (int reg = 0; reg < 4; ++reg)
        acc[reg] = nA[qi * 16 + lk * 4 + reg] + nB[qj * 16 + l15];

    const unsigned short* arow = &Abf[qi * 16 + l15][0];
    const unsigned short* brow = &Bbf[qj * 16 + l15][0];
#pragma unroll
    for (int ks = 0; ks < 4; ++ks) {
        short8 af = *reinterpret_cast<const short8*>(arow + ks * 32 + lk * 8);
        short8 bf = *reinterpret_cast<const short8*>(brow + ks * 32 + lk * 8);
        acc = __builtin_amdgcn_mfma_f32_16x16x32_bf16(af, bf, acc, 0, 0, 0);
    }

#pragma unroll
    for (int reg = 0; reg < 4; ++reg) acc[reg] = fmaxf(acc[reg], 0.f);

    // direct store
#pragma unroll
    for (int reg = 0; reg < 4; ++reg) {
        int row = I + qi * 16 + lk * 4 + reg;
        int col = J + qj * 16 + l15;
        D[(size_t)row * BSZ + col] = acc[reg];
    }

    // mirror store for off-diagonal tiles
    if (bi != bj) {
        int mrow = J + qj * 16 + l15;
        int mcol = I + qi * 16 + lk * 4;
        float4 m = make_float4(acc[0], acc[1], acc[2], acc[3]);
        *reinterpret_cast<float4*>(&D[(size_t)mrow * BSZ + mcol]) = m;
    }
}

__global__ __launch_bounds__(256) void triplet_pass(
    const float* __restrict__ D,
    const int* __restrict__ labels,
    unsigned long long* __restrict__ accs,   // [0]=packed sum+arrivals, [1]=cnt
    float* __restrict__ out)
{
    __shared__ int   lab[BSZ];
    __shared__ float d[BSZ];
    __shared__ unsigned long long masks[8];
    __shared__ int   plist[NPOSMAX];
    __shared__ float wsum[4];
    __shared__ int   wcnt[4];

    const int a = blockIdx.x, tid = threadIdx.x;
    const int wv = tid >> 6, lane = tid & 63;

    lab[tid]       = labels[tid];
    lab[tid + 256] = labels[tid + 256];
    float2 dv = reinterpret_cast<const float2*>(D + (size_t)a * BSZ)[tid];
    d[tid * 2]     = dv.x;
    d[tid * 2 + 1] = dv.y;
    __syncthreads();

    const int la = lab[a];

#pragma unroll
    for (int c = 0; c < 2; ++c) {
        int j = c * 256 + tid;
        unsigned long long m = __ballot(lab[j] == la && j != a);
        if (lane == 0) masks[c * 4 + wv] = m;
    }
    __syncthreads();

    int np = 0;
#pragma unroll
    for (int m = 0; m < 8; ++m) np += __popcll(masks[m]);
    if (np > NPOSMAX) np = NPOSMAX;

#pragma unroll
    for (int c = 0; c < 2; ++c) {
        int j = c * 256 + tid;
        if (lab[j] == la && j != a) {
            int mi = c * 4 + wv, off = 0;
            for (int m = 0; m < mi; ++m) off += __popcll(masks[m]);
            off += __popcll(masks[mi] & ((1ull << lane) - 1ull));
            if (off < NPOSMAX) plist[off] = j;
        }
    }
    __syncthreads();

    float s = 0.f;
    int   cnt = 0;
#pragma unroll
    for (int c = 0; c < 2; ++c) {
        int n = c * 256 + tid;
        if (lab[n] != la) {
            float dn = d[n];
            for (int i = 0; i < np; ++i) {
                float t = fmaxf(d[plist[i]] - dn + 1.0f, 0.f);
                s += t;
                cnt += (t > 1e-16f) ? 1 : 0;
            }
        }
    }

#pragma unroll
    for (int off = 32; off; off >>= 1) {
        s   += __shfl_down(s, off);
        cnt += __shfl_down(cnt, off);
    }
    if (lane == 0) { wsum[wv] = s; wcnt[wv] = cnt; }
    __syncthreads();

    // ---- fused finalize: packed-arrival atomic, no fence ----
    if (tid == 0) {
        float Sb = wsum[0] + wsum[1] + wsum[2] + wsum[3];
        unsigned long long qs = (unsigned long long)llrint((double)Sb * FPSCALE);
        unsigned long long qc = (unsigned long long)(wcnt[0] + wcnt[1] + wcnt[2] + wcnt[3]);

        atomicAdd(&accs[1], qc);                          // count first
        asm volatile("s_waitcnt vmcnt(0)" ::: "memory");  // performed before arrival
        unsigned long long old =
            atomicAdd(&accs[0], qs | (1ull << ARRSHIFT)); // sum + arrival mark
        if ((old >> ARRSHIFT) == (unsigned long long)(BSZ - 1)) {
            // last block: old already holds the other 511 sums
            unsigned long long S = (old & ((1ull << ARRSHIFT) - 1ull)) + qs;
            unsigned long long C = atomicAdd(&accs[1], 0ull);  // all performed
            out[0] = (float)(((double)S / FPSCALE) / ((double)C + 1e-16));
        }
    }
}

extern "C" void kernel_launch(void* const* d_in, const int* in_sizes, int n_in,
                              void* d_out, int out_size, void* d_ws, size_t ws_size,
                              hipStream_t stream)
{
    const float* embs   = reinterpret_cast<const float*>(d_in[0]);
    const int*   labels = reinterpret_cast<const int*>(d_in[1]);
    float*       out    = reinterpret_cast<float*>(d_out);

    float* D = reinterpret_cast<float*>(d_ws);                              // 1 MB
    unsigned long long* accs =
        reinterpret_cast<unsigned long long*>(D + (size_t)BSZ * BSZ);       // 16 B

    dist_mfma_sym<<<136, 256, 0, stream>>>(embs, D, accs);
    triplet_pass<<<BSZ, 256, 0, stream>>>(D, labels, accs, out);
}

// Round 18
// 17.166 us; speedup vs baseline: 3.5353x; 1.5027x over previous
//
#include <hip/hip_runtime.h>
#include <hip/hip_bf16.h>

// BatchAllTripletLoss, B=512, E=128, labels in [0,64), MARGIN=1.0, EPS=1e-16.
// 3-node atomic-free pipeline (proven), repartitioned for block-level TLP:
// K1 dist_mfma_h: 512 blocks (32x16 grid of 16x32 tiles, 2 blocks/CU):
//                 stage 16 A-rows + 32 B-rows as bf16 (B pre-scaled -2) with
//                 exact fp32 norms (proven shfl pattern); waves 0/1 do the
//                 two 16x16 MFMA quadrants (K=128). Same math as R10/R14.
// K2 triplet_h:   1024 blocks x 128 threads (one anchor-half per block,
//                 4 blocks/CU): ballots/plist over 2 waves, hinge on 256
//                 negatives (2/thread), partial per block.
// K3 finalize:    1 block, 1024 threads, reduces 1024 partials.

#define BSZ 512
#define EDIM 128
#define NPOSMAX 96

typedef __attribute__((ext_vector_type(8))) short short8;
typedef __attribute__((ext_vector_type(4))) float f32x4;

__device__ __forceinline__ unsigned short f2bf(float f) {
    __hip_bfloat16 h = __float2bfloat16(f);
    return *reinterpret_cast<unsigned short*>(&h);
}

__global__ __launch_bounds__(256) void dist_mfma_h(
    const float* __restrict__ embs,
    float* __restrict__ D)
{
    __shared__ unsigned short Abf[16][136];
    __shared__ unsigned short Bbf[32][136];   // holds -2*b (exact scale)
    __shared__ float nA[16], nB[32];

    const int tid = threadIdx.x;
    const int bi = blockIdx.x >> 4;           // 0..31 (16-row strip)
    const int bj = blockIdx.x & 15;           // 0..15 (32-col strip)
    const int I = bi * 16, J = bj * 32;
    const int wv = tid >> 6, lane = tid & 63;

    const float4* E4 = reinterpret_cast<const float4*>(embs);

    // ---- stage A (16 rows) ----
#pragma unroll
    for (int q = 0; q < 2; ++q) {
        int idx = tid + 256 * q;              // 0..511
        int r = idx >> 5, k4 = idx & 31;
        float4 v = E4[(size_t)(I + r) * (EDIM / 4) + k4];
        float s = v.x * v.x + v.y * v.y + v.z * v.z + v.w * v.w;
        s += __shfl_xor(s, 1); s += __shfl_xor(s, 2); s += __shfl_xor(s, 4);
        s += __shfl_xor(s, 8); s += __shfl_xor(s, 16);
        if ((tid & 31) == 0) nA[r] = s;
        ushort4 u = { f2bf(v.x), f2bf(v.y), f2bf(v.z), f2bf(v.w) };
        *reinterpret_cast<ushort4*>(&Abf[r][k4 * 4]) = u;
    }
    // ---- stage B (32 rows), pre-scaled by -2 ----
#pragma unroll
    for (int q = 0; q < 4; ++q) {
        int idx = tid + 256 * q;              // 0..1023
        int r = idx >> 5, k4 = idx & 31;
        float4 v = E4[(size_t)(J + r) * (EDIM / 4) + k4];
        float s = v.x * v.x + v.y * v.y + v.z * v.z + v.w * v.w;
        s += __shfl_xor(s, 1); s += __shfl_xor(s, 2); s += __shfl_xor(s, 4);
        s += __shfl_xor(s, 8); s += __shfl_xor(s, 16);
        if ((tid & 31) == 0) nB[r] = s;
        ushort4 u = { f2bf(-2.f * v.x), f2bf(-2.f * v.y),
                      f2bf(-2.f * v.z), f2bf(-2.f * v.w) };
        *reinterpret_cast<ushort4*>(&Bbf[r][k4 * 4]) = u;
    }
    __syncthreads();

    // ---- MFMA: waves 0/1 -> col half qj = wv ----
    if (wv < 2) {
        const int qj = wv;
        const int l15 = lane & 15, lk = lane >> 4;

        f32x4 acc;
#pragma unroll
        for (int reg = 0; reg < 4; ++reg)
            acc[reg] = nA[lk * 4 + reg] + nB[qj * 16 + l15];

        const unsigned short* arow = &Abf[l15][0];
        const unsigned short* brow = &Bbf[qj * 16 + l15][0];
#pragma unroll
        for (int ks = 0; ks < 4; ++ks) {
            short8 af = *reinterpret_cast<const short8*>(arow + ks * 32 + lk * 8);
            short8 bf = *reinterpret_cast<const short8*>(brow + ks * 32 + lk * 8);
            acc = __builtin_amdgcn_mfma_f32_16x16x32_bf16(af, bf, acc, 0, 0, 0);
        }
#pragma unroll
        for (int reg = 0; reg < 4; ++reg) {
            int row = I + lk * 4 + reg;
            int col = J + qj * 16 + l15;
            D[(size_t)row * BSZ + col] = fmaxf(acc[reg], 0.f);
        }
    }
}

__global__ __launch_bounds__(128) void triplet_h(
    const float* __restrict__ D,
    const int* __restrict__ labels,
    float* __restrict__ sums,
    float* __restrict__ cnts)
{
    __shared__ int   lab[BSZ];
    __shared__ float d[BSZ];
    __shared__ unsigned long long masks[8];
    __shared__ int   plist[NPOSMAX];
    __shared__ float wsum[2];
    __shared__ int   wcnt[2];

    const int b = blockIdx.x, tid = threadIdx.x;
    const int a = b >> 1, h = b & 1;
    const int wv = tid >> 6, lane = tid & 63;

    // stage labels (4/thread) + full D row (4 floats/thread)
#pragma unroll
    for (int q = 0; q < 4; ++q) lab[tid + 128 * q] = labels[tid + 128 * q];
    float4 dv = reinterpret_cast<const float4*>(D + (size_t)a * BSZ)[tid];
    d[tid * 4 + 0] = dv.x; d[tid * 4 + 1] = dv.y;
    d[tid * 4 + 2] = dv.z; d[tid * 4 + 3] = dv.w;
    __syncthreads();

    const int la = lab[a];

    // ballots: wave wv covers chunks {2c+wv}
#pragma unroll
    for (int c = 0; c < 4; ++c) {
        int mi = c * 2 + wv;
        int j = mi * 64 + lane;
        unsigned long long m = __ballot(lab[j] == la && j != a);
        if (lane == 0) masks[mi] = m;
    }
    __syncthreads();

    int np = 0;
#pragma unroll
    for (int m = 0; m < 8; ++m) np += __popcll(masks[m]);
    if (np > NPOSMAX) np = NPOSMAX;

#pragma unroll
    for (int c = 0; c < 4; ++c) {
        int mi = c * 2 + wv;
        int j = mi * 64 + lane;
        if (lab[j] == la && j != a) {
            int off = 0;
            for (int m = 0; m < mi; ++m) off += __popcll(masks[m]);
            off += __popcll(masks[mi] & ((1ull << lane) - 1ull));
            if (off < NPOSMAX) plist[off] = j;
        }
    }
    __syncthreads();

    // hinge: this block's half = negatives [h*256, h*256+256), 2 per thread
    float s = 0.f;
    int   cnt = 0;
#pragma unroll
    for (int c = 0; c < 2; ++c) {
        int n = h * 256 + c * 128 + tid;
        if (lab[n] != la) {
            float dn = d[n];
            for (int i = 0; i < np; ++i) {
                float t = fmaxf(d[plist[i]] - dn + 1.0f, 0.f);
                s += t;
                cnt += (t > 1e-16f) ? 1 : 0;
            }
        }
    }

#pragma unroll
    for (int off = 32; off; off >>= 1) {
        s   += __shfl_down(s, off);
        cnt += __shfl_down(cnt, off);
    }
    if (lane == 0) { wsum[wv] = s; wcnt[wv] = cnt; }
    __syncthreads();
    if (tid == 0) {
        sums[b] = wsum[0] + wsum[1];
        cnts[b] = (float)(wcnt[0] + wcnt[1]);
    }
}

__global__ __launch_bounds__(1024) void finalize(
    const float* __restrict__ sums,
    const float* __restrict__ cnts,
    float* __restrict__ out)
{
    __shared__ float fsum[16], fcnt[16];
    const int tid = threadIdx.x;
    float s = sums[tid];
    float c = cnts[tid];
#pragma unroll
    for (int off = 32; off; off >>= 1) {
        s += __shfl_down(s, off);
        c += __shfl_down(c, off);
    }
    const int wv = tid >> 6, lane = tid & 63;
    if (lane == 0) { fsum[wv] = s; fcnt[wv] = c; }
    __syncthreads();
    if (tid == 0) {
        float S = 0.f, C = 0.f;
#pragma unroll
        for (int w = 0; w < 16; ++w) { S += fsum[w]; C += fcnt[w]; }
        out[0] = S / (C + 1e-16f);
    }
}

extern "C" void kernel_launch(void* const* d_in, const int* in_sizes, int n_in,
                              void* d_out, int out_size, void* d_ws, size_t ws_size,
                              hipStream_t stream)
{
    const float* embs   = reinterpret_cast<const float*>(d_in[0]);
    const int*   labels = reinterpret_cast<const int*>(d_in[1]);
    float*       out    = reinterpret_cast<float*>(d_out);

    float* D    = reinterpret_cast<float*>(d_ws);                 // 1 MB
    float* sums = D + (size_t)BSZ * BSZ;                          // 4 KB
    float* cnts = sums + 1024;                                    // 4 KB

    dist_mfma_h<<<512, 256, 0, stream>>>(embs, D);
    triplet_h<<<1024, 128, 0, stream>>>(D, labels, sums, cnts);
    finalize<<<1, 1024, 0, stream>>>(sums, cnts, out);
}

// Round 19
// 15.715 us; speedup vs baseline: 3.8616x; 1.0923x over previous
//
#include <hip/hip_runtime.h>
#include <hip/hip_bf16.h>

// BatchAllTripletLoss, B=512, E=128, labels in [0,64), MARGIN=1.0, EPS=1e-16.
// Champion structure (R14 bench: 15.65us) with ONE variable changed:
// K1 dist_mfma_h: 512 blocks (32x16 grid of 16x32 tiles, 2 blocks/CU) instead
//                 of 136x(32x32). Stage 16 A-rows + 32 B-rows bf16 (B scaled
//                 -2, exact) + exact fp32 norms; waves 0/1 do two 16x16 MFMA
//                 quadrants (K=128). Same math -> bit-identical D.
// K2 triplet_pass: byte-identical champion (512 blocks, 1 anchor each).
// K3 finalize:     byte-identical champion (1 block, 512 threads).
// No atomics -> deterministic.

#define BSZ 512
#define EDIM 128
#define NPOSMAX 96

typedef __attribute__((ext_vector_type(8))) short short8;
typedef __attribute__((ext_vector_type(4))) float f32x4;

__device__ __forceinline__ unsigned short f2bf(float f) {
    __hip_bfloat16 h = __float2bfloat16(f);
    return *reinterpret_cast<unsigned short*>(&h);
}

__global__ __launch_bounds__(256) void dist_mfma_h(
    const float* __restrict__ embs,
    float* __restrict__ D)
{
    __shared__ unsigned short Abf[16][136];
    __shared__ unsigned short Bbf[32][136];   // holds -2*b (exact scale)
    __shared__ float nA[16], nB[32];

    const int tid = threadIdx.x;
    const int bi = blockIdx.x >> 4;           // 0..31 (16-row strip)
    const int bj = blockIdx.x & 15;           // 0..15 (32-col strip)
    const int I = bi * 16, J = bj * 32;
    const int wv = tid >> 6, lane = tid & 63;

    const float4* E4 = reinterpret_cast<const float4*>(embs);

    // ---- stage A (16 rows) ----
#pragma unroll
    for (int q = 0; q < 2; ++q) {
        int idx = tid + 256 * q;              // 0..511
        int r = idx >> 5, k4 = idx & 31;
        float4 v = E4[(size_t)(I + r) * (EDIM / 4) + k4];
        float s = v.x * v.x + v.y * v.y + v.z * v.z + v.w * v.w;
        s += __shfl_xor(s, 1); s += __shfl_xor(s, 2); s += __shfl_xor(s, 4);
        s += __shfl_xor(s, 8); s += __shfl_xor(s, 16);
        if ((tid & 31) == 0) nA[r] = s;
        ushort4 u = { f2bf(v.x), f2bf(v.y), f2bf(v.z), f2bf(v.w) };
        *reinterpret_cast<ushort4*>(&Abf[r][k4 * 4]) = u;
    }
    // ---- stage B (32 rows), pre-scaled by -2 ----
#pragma unroll
    for (int q = 0; q < 4; ++q) {
        int idx = tid + 256 * q;              // 0..1023
        int r = idx >> 5, k4 = idx & 31;
        float4 v = E4[(size_t)(J + r) * (EDIM / 4) + k4];
        float s = v.x * v.x + v.y * v.y + v.z * v.z + v.w * v.w;
        s += __shfl_xor(s, 1); s += __shfl_xor(s, 2); s += __shfl_xor(s, 4);
        s += __shfl_xor(s, 8); s += __shfl_xor(s, 16);
        if ((tid & 31) == 0) nB[r] = s;
        ushort4 u = { f2bf(-2.f * v.x), f2bf(-2.f * v.y),
                      f2bf(-2.f * v.z), f2bf(-2.f * v.w) };
        *reinterpret_cast<ushort4*>(&Bbf[r][k4 * 4]) = u;
    }
    __syncthreads();

    // ---- MFMA: waves 0/1 -> col half qj = wv ----
    if (wv < 2) {
        const int qj = wv;
        const int l15 = lane & 15, lk = lane >> 4;

        f32x4 acc;
#pragma unroll
        for (int reg = 0; reg < 4; ++reg)
            acc[reg] = nA[lk * 4 + reg] + nB[qj * 16 + l15];

        const unsigned short* arow = &Abf[l15][0];
        const unsigned short* brow = &Bbf[qj * 16 + l15][0];
#pragma unroll
        for (int ks = 0; ks < 4; ++ks) {
            short8 af = *reinterpret_cast<const short8*>(arow + ks * 32 + lk * 8);
            short8 bf = *reinterpret_cast<const short8*>(brow + ks * 32 + lk * 8);
            acc = __builtin_amdgcn_mfma_f32_16x16x32_bf16(af, bf, acc, 0, 0, 0);
        }
#pragma unroll
        for (int reg = 0; reg < 4; ++reg) {
            int row = I + lk * 4 + reg;
            int col = J + qj * 16 + l15;
            D[(size_t)row * BSZ + col] = fmaxf(acc[reg], 0.f);
        }
    }
}

__global__ __launch_bounds__(256) void triplet_pass(
    const float* __restrict__ D,
    const int* __restrict__ labels,
    float* __restrict__ sums,
    float* __restrict__ cnts)
{
    __shared__ int   lab[BSZ];
    __shared__ float d[BSZ];
    __shared__ unsigned long long masks[8];
    __shared__ int   plist[NPOSMAX];
    __shared__ float wsum[4];
    __shared__ int   wcnt[4];

    const int a = blockIdx.x, tid = threadIdx.x;
    const int wv = tid >> 6, lane = tid & 63;

    lab[tid]       = labels[tid];
    lab[tid + 256] = labels[tid + 256];
    float2 dv = reinterpret_cast<const float2*>(D + (size_t)a * BSZ)[tid];
    d[tid * 2]     = dv.x;
    d[tid * 2 + 1] = dv.y;
    __syncthreads();

    const int la = lab[a];

#pragma unroll
    for (int c = 0; c < 2; ++c) {
        int j = c * 256 + tid;
        unsigned long long m = __ballot(lab[j] == la && j != a);
        if (lane == 0) masks[c * 4 + wv] = m;
    }
    __syncthreads();

    int np = 0;
#pragma unroll
    for (int m = 0; m < 8; ++m) np += __popcll(masks[m]);
    if (np > NPOSMAX) np = NPOSMAX;

#pragma unroll
    for (int c = 0; c < 2; ++c) {
        int j = c * 256 + tid;
        if (lab[j] == la && j != a) {
            int mi = c * 4 + wv, off = 0;
            for (int m = 0; m < mi; ++m) off += __popcll(masks[m]);
            off += __popcll(masks[mi] & ((1ull << lane) - 1ull));
            if (off < NPOSMAX) plist[off] = j;
        }
    }
    __syncthreads();

    float s = 0.f;
    int   cnt = 0;
#pragma unroll
    for (int c = 0; c < 2; ++c) {
        int n = c * 256 + tid;
        if (lab[n] != la) {
            float dn = d[n];
            for (int i = 0; i < np; ++i) {
                float t = fmaxf(d[plist[i]] - dn + 1.0f, 0.f);
                s += t;
                cnt += (t > 1e-16f) ? 1 : 0;
            }
        }
    }

#pragma unroll
    for (int off = 32; off; off >>= 1) {
        s   += __shfl_down(s, off);
        cnt += __shfl_down(cnt, off);
    }
    if (lane == 0) { wsum[wv] = s; wcnt[wv] = cnt; }
    __syncthreads();
    if (tid == 0) {
        sums[a] = wsum[0] + wsum[1] + wsum[2] + wsum[3];
        cnts[a] = (float)(wcnt[0] + wcnt[1] + wcnt[2] + wcnt[3]);
    }
}

__global__ __launch_bounds__(512) void finalize(
    const float* __restrict__ sums,
    const float* __restrict__ cnts,
    float* __restrict__ out)
{
    __shared__ float wsum[8], wcnt[8];
    const int tid = threadIdx.x;
    float s = sums[tid];
    float c = cnts[tid];
#pragma unroll
    for (int off = 32; off; off >>= 1) {
        s += __shfl_down(s, off);
        c += __shfl_down(c, off);
    }
    const int wv = tid >> 6, lane = tid & 63;
    if (lane == 0) { wsum[wv] = s; wcnt[wv] = c; }
    __syncthreads();
    if (tid == 0) {
        float S = 0.f, C = 0.f;
#pragma unroll
        for (int w = 0; w < 8; ++w) { S += wsum[w]; C += wcnt[w]; }
        out[0] = S / (C + 1e-16f);
    }
}

extern "C" void kernel_launch(void* const* d_in, const int* in_sizes, int n_in,
                              void* d_out, int out_size, void* d_ws, size_t ws_size,
                              hipStream_t stream)
{
    const float* embs   = reinterpret_cast<const float*>(d_in[0]);
    const int*   labels = reinterpret_cast<const int*>(d_in[1]);
    float*       out    = reinterpret_cast<float*>(d_out);

    float* D    = reinterpret_cast<float*>(d_ws);                 // 1 MB
    float* sums = D + (size_t)BSZ * BSZ;                          // 2 KB
    float* cnts = sums + BSZ;                                     // 2 KB

    dist_mfma_h<<<512, 256, 0, stream>>>(embs, D);
    triplet_pass<<<BSZ, 256, 0, stream>>>(D, labels, sums, cnts);
    finalize<<<1, 512, 0, stream>>>(sums, cnts, out);
}